// Round 9
// baseline (503.257 us; speedup 1.0000x reference)
//
#include <hip/hip_runtime.h>
#include <hip/hip_bf16.h>

typedef unsigned short u16;
typedef unsigned int   u32;
typedef __attribute__((ext_vector_type(8))) short bf16x8;
typedef __attribute__((ext_vector_type(4))) float f32x4;

#define FDIM 1024
#define NH   16
#define HD   64
#define SEQ  2048

#define MFMA16 __builtin_amdgcn_mfma_f32_16x16x32_bf16

__device__ __forceinline__ u16 f2bf(float f) {
    __hip_bfloat16 h = __float2bfloat16(f);
    return *reinterpret_cast<u16*>(&h);
}

// async global->LDS, 16B per lane. LDS dest is wave-uniform base + lane*16.
__device__ __forceinline__ void g2l16(const u16* g, u16* l) {
    __builtin_amdgcn_global_load_lds(
        (const __attribute__((address_space(1))) unsigned int*)g,
        (__attribute__((address_space(3))) unsigned int*)l,
        16, 0, 0);
}

// v_exp_f32: D = 2^S0 (register-only inline asm; no memory ordering concerns)
__device__ __forceinline__ float exp2v(float x) {
    float d;
    asm("v_exp_f32 %0, %1" : "=v"(d) : "v"(x));
    return d;
}

// RNE f32->bf16 pair pack (valid for finite values; P in [0,1])
__device__ __forceinline__ u32 bfpack(float a, float b) {
    u32 ua = __float_as_uint(a), ub = __float_as_uint(b);
    return ((ua + 0x7FFF + ((ua >> 16) & 1)) >> 16)
         | ((ub + 0x7FFF + ((ub >> 16) & 1)) & 0xFFFF0000u);
}

// =====================================================================
// One-shot fp32 -> bf16 conversion of X (both batches, re+im).
// =====================================================================
__global__ __launch_bounds__(256)
void convert_x(const float* __restrict__ xr, const float* __restrict__ xi,
               u16* __restrict__ dr, u16* __restrict__ di)
{
    const long n4 = (long)2 * SEQ * FDIM / 4;
    for (long i = (long)blockIdx.x * blockDim.x + threadIdx.x; i < n4;
         i += (long)gridDim.x * blockDim.x) {
        float4 v = ((const float4*)xr)[i];
        ushort4 o;
        o.x = f2bf(v.x); o.y = f2bf(v.y); o.z = f2bf(v.z); o.w = f2bf(v.w);
        ((ushort4*)dr)[i] = o;
        v = ((const float4*)xi)[i];
        o.x = f2bf(v.x); o.y = f2bf(v.y); o.z = f2bf(v.z); o.w = f2bf(v.w);
        ((ushort4*)di)[i] = o;
    }
}

// =====================================================================
// One-shot fp32 W [k][n] -> bf16 W^T [n][k] for all 8 weight matrices.
// =====================================================================
__global__ __launch_bounds__(256)
void convert_w(const float* __restrict__ W0, const float* __restrict__ W1,
               const float* __restrict__ W2, const float* __restrict__ W3,
               const float* __restrict__ W4, const float* __restrict__ W5,
               const float* __restrict__ W6, const float* __restrict__ W7,
               u16* __restrict__ wt_base)
{
    __shared__ u16 T[64][68];
    const int z = blockIdx.z;
    const float* W = (z == 0) ? W0 : (z == 1) ? W1 : (z == 2) ? W2 : (z == 3) ? W3
                   : (z == 4) ? W4 : (z == 5) ? W5 : (z == 6) ? W6 : W7;
    u16* Wt = wt_base + (long)z * FDIM * FDIM;
    const int n0 = blockIdx.x * 64, k0 = blockIdx.y * 64;
    const int tid = threadIdx.x;
    const int cr = tid & 15, rr = tid >> 4;
    #pragma unroll
    for (int p = 0; p < 4; p++) {
        const int k = p * 16 + rr;
        float4 v = *(const float4*)&W[(long)(k0 + k) * FDIM + n0 + cr * 4];
        T[k][cr*4 + 0] = f2bf(v.x); T[k][cr*4 + 1] = f2bf(v.y);
        T[k][cr*4 + 2] = f2bf(v.z); T[k][cr*4 + 3] = f2bf(v.w);
    }
    __syncthreads();
    #pragma unroll
    for (int p = 0; p < 4; p++) {
        const int n = p * 16 + rr;
        ushort4 o;
        o.x = T[cr*4 + 0][n]; o.y = T[cr*4 + 1][n];
        o.z = T[cr*4 + 2][n]; o.w = T[cr*4 + 3][n];
        *(ushort4*)&Wt[(long)(n0 + n) * FDIM + k0 + cr*4] = o;
    }
}

// =====================================================================
// Projection GEMM v3 (verified round 3): pure bf16, double-buffered
// one-tile-ahead prefetch, chunk-swizzled LDS.
// =====================================================================
__global__ __launch_bounds__(256)
void proj_bf16(const u16* __restrict__ Xr_g, const u16* __restrict__ Xi_g,
               const u16* __restrict__ Wt_base,
               const float* __restrict__ bqr, const float* __restrict__ bqi,
               const float* __restrict__ bkr, const float* __restrict__ bki,
               const float* __restrict__ bvr, const float* __restrict__ bvi,
               u16* __restrict__ ws)
{
    __shared__ u16 XsR[2][128 * 32], XsI[2][128 * 32];
    __shared__ u16 WsR[2][128 * 32], WsI[2][128 * 32];

    const int z = blockIdx.z, t = z % 3, b = z / 3;
    const u16* xr = Xr_g + (long)b * SEQ * FDIM;
    const u16* xi = Xi_g + (long)b * SEQ * FDIM;
    const long WT = (long)FDIM * FDIM;
    const u16* wr = Wt_base + (long)(2 * t) * WT;
    const u16* wi = wr + WT;
    const float* br = (t == 0) ? bqr : (t == 1) ? bkr : bvr;
    const float* bi = (t == 0) ? bqi : (t == 1) ? bki : bvi;
    const long TS = (long)2 * SEQ * FDIM;
    u16* outR = ws + (long)(t * 2) * TS + (long)b * SEQ * FDIM;
    u16* outI = outR + TS;

    const int tid = threadIdx.x;
    const int n0  = blockIdx.x * 128;
    const int m0  = blockIdx.y * 128;

    const int lane = tid & 63;
    const int wv   = tid >> 6;
    const int mwo  = (wv >> 1) * 64;
    const int nwo  = (wv & 1) * 64;
    const int ml   = lane & 15;
    const int kg   = lane >> 4;

    const int lr = lane >> 2;
    const int xc = (((lane & 3) ^ (lr & 3)) * 8);
    const int rc = ((kg ^ (ml & 3)) * 8);

    f32x4 accr[4][4], acci[4][4];
    #pragma unroll
    for (int i = 0; i < 4; i++)
        #pragma unroll
        for (int j = 0; j < 4; j++) { accr[i][j] = (f32x4)(0.0f); acci[i][j] = (f32x4)(0.0f); }

    #define PSTAGE(bufi, kk)                                                     \
        do {                                                                     \
            _Pragma("unroll")                                                    \
            for (int sub = 0; sub < 2; sub++) {                                  \
                const int rs  = wv * 32 + sub * 16;                              \
                const int row = rs + lr;                                         \
                g2l16(xr + (long)(m0 + row) * FDIM + (kk) + xc, &XsR[bufi][rs * 32]); \
                g2l16(xi + (long)(m0 + row) * FDIM + (kk) + xc, &XsI[bufi][rs * 32]); \
                g2l16(wr + (long)(n0 + row) * FDIM + (kk) + xc, &WsR[bufi][rs * 32]); \
                g2l16(wi + (long)(n0 + row) * FDIM + (kk) + xc, &WsI[bufi][rs * 32]); \
            }                                                                    \
        } while (0)

    int buf = 0;
    PSTAGE(0, 0);
    __syncthreads();

    for (int k0 = 0; k0 < FDIM; k0 += 32) {
        if (k0 + 32 < FDIM) PSTAGE(buf ^ 1, k0 + 32);

        bf16x8 ar[4], ai[4], nai[4], brf[4], bif[4];
        #pragma unroll
        for (int i = 0; i < 4; i++) {
            ar[i] = *(const bf16x8*)&XsR[buf][(mwo + 16*i + ml) * 32 + rc];
            union { bf16x8 v; u32 w[4]; } u;
            u.v = *(const bf16x8*)&XsI[buf][(mwo + 16*i + ml) * 32 + rc];
            ai[i] = u.v;
            u.w[0] ^= 0x80008000u; u.w[1] ^= 0x80008000u;
            u.w[2] ^= 0x80008000u; u.w[3] ^= 0x80008000u;
            nai[i] = u.v;
        }
        #pragma unroll
        for (int j = 0; j < 4; j++) {
            brf[j] = *(const bf16x8*)&WsR[buf][(nwo + 16*j + ml) * 32 + rc];
            bif[j] = *(const bf16x8*)&WsI[buf][(nwo + 16*j + ml) * 32 + rc];
        }
        #pragma unroll
        for (int i = 0; i < 4; i++)
            #pragma unroll
            for (int j = 0; j < 4; j++) {
                accr[i][j] = MFMA16(ar[i],  brf[j], accr[i][j], 0, 0, 0);
                accr[i][j] = MFMA16(nai[i], bif[j], accr[i][j], 0, 0, 0);
                acci[i][j] = MFMA16(ar[i],  bif[j], acci[i][j], 0, 0, 0);
                acci[i][j] = MFMA16(ai[i],  brf[j], acci[i][j], 0, 0, 0);
            }

        __syncthreads();
        buf ^= 1;
    }
    #undef PSTAGE

    #pragma unroll
    for (int j = 0; j < 4; j++) {
        const int n = n0 + nwo + 16*j + ml;
        const int hh = n >> 6, d = n & 63;
        const float bre = br[n];
        const float bim = bi[n];
        #pragma unroll
        for (int i = 0; i < 4; i++) {
            const int mb = m0 + mwo + 16*i + kg*4;
            if (t < 2) {
                #pragma unroll
                for (int r = 0; r < 4; r++) {
                    const long addr = ((long)hh * SEQ + (mb + r)) * HD + d;
                    outR[addr] = f2bf(accr[i][j][r] + bre);
                    outI[addr] = f2bf(acci[i][j][r] + bim);
                }
            } else {
                const long addr = ((long)hh * HD + d) * SEQ + mb;
                ushort4 vr, vi;
                vr.x = f2bf(accr[i][j][0] + bre); vr.y = f2bf(accr[i][j][1] + bre);
                vr.z = f2bf(accr[i][j][2] + bre); vr.w = f2bf(accr[i][j][3] + bre);
                vi.x = f2bf(acci[i][j][0] + bim); vi.y = f2bf(acci[i][j][1] + bim);
                vi.z = f2bf(acci[i][j][2] + bim); vi.w = f2bf(acci[i][j][3] + bim);
                *(ushort4*)&outR[addr] = vr;
                *(ushort4*)&outI[addr] = vi;
            }
        }
    }
}

// =====================================================================
// MFMA flash attention v5 (evolved from verified v2c):
//   (new 1) mask precomputed into LDS madd (log2e folded) in prologue ->
//           NO per-tile VMEM consumer -> no mid-tile vmcnt drain; the
//           8 prefetch loads stay in flight for the whole tile.
//   (new 2) softmax in exp2 domain (scale*log2e folded; v_exp_f32 direct)
//   (new 3) defer-max THR=0 (exact): skip alpha broadcast + O rescale
//           when running max did not grow (wave-uniform branch)
//   (new 4) cheap RNE bf16 pair-pack for P
// Kept verified: STAGE-at-top dbuf, chunk swizzle, P alias in dead K,
// raw mid barrier, end-of-tile __syncthreads, XCD swizzle, tree reduce.
// =====================================================================
__global__ __launch_bounds__(256)
void attn_mfma(const u16* __restrict__ Qr_g, const u16* __restrict__ Qi_g,
               const u16* __restrict__ Kr_g, const u16* __restrict__ Ki_g,
               const u16* __restrict__ Vtr_g, const u16* __restrict__ Vti_g,
               const float* __restrict__ mask_g,
               u16* __restrict__ Ar_g, u16* __restrict__ Ai_g)
{
    __shared__ u16 KT[2][64 * 128];   // [key][dim 0..127 = re||im], chunk-swizzled
    __shared__ u16 VT[2][128 * 64];   // [dim re||im][key], chunk-swizzled
    __shared__ float madd_l[SEQ];     // (1-mask)*-1e9*log2e, filled once

    const int tid  = threadIdx.x;
    const int lane = tid & 63;
    const int wv   = tid >> 6;
    const int ml   = lane & 15;
    const int quad = lane >> 4;

    // ---- XCD swizzle: 16 q-blocks of one (h,b) share an XCD ----
    const int L   = blockIdx.x + (blockIdx.y << 4) + (blockIdx.z << 8);
    const int xcd = L & 7, qq = L >> 3;
    const int q0  = (qq & 15) * 128;
    const int g   = ((qq >> 4) << 3) | xcd;
    const int h   = g & 15;
    const int b   = g >> 4;
    const long hb  = ((long)b * NH + h) * SEQ * HD;
    const float* mask = mask_g + (long)b * SEQ;

    // ---- Q fragments, in registers for the whole kernel ----
    bf16x8 qf[2][4];
    #pragma unroll
    for (int nt = 0; nt < 2; nt++) {
        const long row = hb + (long)(q0 + wv*32 + nt*16 + ml) * HD;
        qf[nt][0] = *(const bf16x8*)(Qr_g + row + quad*8);
        qf[nt][1] = *(const bf16x8*)(Qr_g + row + 32 + quad*8);
        qf[nt][2] = *(const bf16x8*)(Qi_g + row + quad*8);
        qf[nt][3] = *(const bf16x8*)(Qi_g + row + 32 + quad*8);
    }

    // ---- staging source pointers (pre-swizzled, lane-constant) ----
    const u16* srcK[4];
    #pragma unroll
    for (int ii = 0; ii < 4; ii++) {
        const int rk = wv*16 + ii*4 + (lane >> 4);
        const int c  = (lane & 15) ^ (rk & 7);
        srcK[ii] = ((c < 8) ? Kr_g : Ki_g) + hb + (long)rk * HD + (c & 7) * 8;
    }
    const u16* srcV[4];
    #pragma unroll
    for (int jj = 0; jj < 4; jj++) {
        const int dv = wv*32 + jj*8 + (lane >> 3);
        const int c  = (lane & 7) ^ (dv & 7);
        srcV[jj] = ((dv < 64) ? Vtr_g : Vti_g) + hb + (long)(dv & 63) * SEQ + c * 8;
    }

    #define STAGE(bufi)                                                         \
        do {                                                                    \
            _Pragma("unroll")                                                   \
            for (int ii = 0; ii < 4; ii++)                                      \
                g2l16(srcK[ii], &KT[bufi][(wv*16 + ii*4) * 128]);               \
            _Pragma("unroll")                                                   \
            for (int jj = 0; jj < 4; jj++)                                      \
                g2l16(srcV[jj], &VT[bufi][(wv*32 + jj*8) * 64]);                \
            _Pragma("unroll")                                                   \
            for (int ii = 0; ii < 4; ii++) srcK[ii] += 64 * HD;                 \
            _Pragma("unroll")                                                   \
            for (int jj = 0; jj < 4; jj++) srcV[jj] += 64;                      \
        } while (0)

    f32x4 oacc[2][8];
    #pragma unroll
    for (int mt = 0; mt < 2; mt++)
        #pragma unroll
        for (int nt = 0; nt < 8; nt++) oacc[mt][nt] = (f32x4)(0.0f);
    float m_run[2] = {-3.0e38f, -3.0e38f};
    float l_run[2] = {0.0f, 0.0f};
    const float SCALE2 = 0.125f * 1.44269504088896f;   // 0.125 * log2(e)

    STAGE(0);
    // fill madd once (coalesced; log2e folded)
    #pragma unroll
    for (int i = 0; i < SEQ / 256; i++)
        madd_l[tid + 256 * i] = (1.0f - mask[tid + 256 * i]) * (-1.0e9f * 1.44269504f);
    __syncthreads();

    const int NT = SEQ / 64;
    for (int t = 0; t < NT; ++t) {
        const int cur = t & 1;
        if (t + 1 < NT) STAGE(cur ^ 1);   // prefetch; nothing waits on it until tile end

        // mask adders from LDS (read-only region; no hazard with staging)
        f32x4 mdv[4];
        #pragma unroll
        for (int mt = 0; mt < 4; mt++)
            mdv[mt] = *(const f32x4*)&madd_l[t*64 + mt*16 + quad*4];

        // ---- scores: S^T[key][q] ----
        f32x4 sacc[4][2];
        #pragma unroll
        for (int mt = 0; mt < 4; mt++) { sacc[mt][0] = (f32x4)(0.0f); sacc[mt][1] = (f32x4)(0.0f); }
        const u16* Kc = &KT[cur][0];
        __builtin_amdgcn_s_setprio(1);
        #pragma unroll
        for (int mt = 0; mt < 4; mt++)
            #pragma unroll
            for (int kc = 0; kc < 4; kc++) {
                const bf16x8 kf = *(const bf16x8*)
                    &Kc[(mt*16 + ml) * 128 + (((kc*4 + quad) ^ (ml & 7)) * 8)];
                sacc[mt][0] = MFMA16(kf, qf[0][kc], sacc[mt][0], 0, 0, 0);
                sacc[mt][1] = MFMA16(kf, qf[1][kc], sacc[mt][1], 0, 0, 0);
            }
        __builtin_amdgcn_s_setprio(0);

        // all waves done reading K[cur]; P may overwrite it. Raw barrier:
        // prefetch stays in flight.
        asm volatile("s_barrier" ::: "memory");

        u16* Pb = (u16*)&KT[cur][0];   // alias: P as [128][64], same swizzle
        float alSave[2];
        int need = 0;
        #pragma unroll
        for (int nt = 0; nt < 2; nt++) {
            float sv[4][4];
            #pragma unroll
            for (int mt = 0; mt < 4; mt++)
                #pragma unroll
                for (int r = 0; r < 4; r++)
                    sv[mt][r] = sacc[mt][nt][r] * SCALE2 + mdv[mt][r];

            // tree max (depth 4)
            float mA = fmaxf(fmaxf(sv[0][0], sv[0][1]), fmaxf(sv[0][2], sv[0][3]));
            float mB = fmaxf(fmaxf(sv[1][0], sv[1][1]), fmaxf(sv[1][2], sv[1][3]));
            float mC = fmaxf(fmaxf(sv[2][0], sv[2][1]), fmaxf(sv[2][2], sv[2][3]));
            float mD = fmaxf(fmaxf(sv[3][0], sv[3][1]), fmaxf(sv[3][2], sv[3][3]));
            float mx = fmaxf(fmaxf(mA, mB), fmaxf(mC, mD));
            mx = fmaxf(mx, __shfl_xor(mx, 16));
            mx = fmaxf(mx, __shfl_xor(mx, 32));

            // defer-max THR=0 (exact): skip rescale path when max didn't grow
            const int grow = __any(mx > m_run[nt]);
            float mn, al;
            if (grow) { mn = fmaxf(m_run[nt], mx); al = exp2v(m_run[nt] - mn); }
            else      { mn = m_run[nt];            al = 1.0f; }
            need |= grow;

            float p[4][4];
            #pragma unroll
            for (int mt = 0; mt < 4; mt++) {
                p[mt][0] = exp2v(sv[mt][0] - mn);
                p[mt][1] = exp2v(sv[mt][1] - mn);
                p[mt][2] = exp2v(sv[mt][2] - mn);
                p[mt][3] = exp2v(sv[mt][3] - mn);
            }
            const int qrow = wv*32 + nt*16 + ml;
            #pragma unroll
            for (int mt = 0; mt < 4; mt++) {
                uint2 pw;
                pw.x = bfpack(p[mt][0], p[mt][1]);
                pw.y = bfpack(p[mt][2], p[mt][3]);
                *(uint2*)&Pb[(long)qrow * 64
                             + (((mt*2 + (quad >> 1)) ^ (ml & 7)) * 8)
                             + (quad & 1) * 4] = pw;
            }
            // tree sum
            float s0 = (p[0][0] + p[0][1]) + (p[0][2] + p[0][3]);
            float s1 = (p[1][0] + p[1][1]) + (p[1][2] + p[1][3]);
            float s2 = (p[2][0] + p[2][1]) + (p[2][2] + p[2][3]);
            float s3 = (p[3][0] + p[3][1]) + (p[3][2] + p[3][3]);
            float ps = (s0 + s1) + (s2 + s3);
            ps += __shfl_xor(ps, 16);
            ps += __shfl_xor(ps, 32);
            l_run[nt] = l_run[nt] * al + ps;
            m_run[nt] = mn;
            alSave[nt] = al;
        }

        // rescale O only when some row's max grew (wave-uniform branch)
        if (need) {
            f32x4 al4[2];
            #pragma unroll
            for (int mt = 0; mt < 2; mt++)
                #pragma unroll
                for (int r = 0; r < 4; r++)
                    al4[mt][r] = __shfl(alSave[mt], quad*20 + r);
            #pragma unroll
            for (int mt = 0; mt < 2; mt++)
                #pragma unroll
                for (int nt = 0; nt < 8; nt++) oacc[mt][nt] *= al4[mt];
        }

        // ---- PV ----
        const u16* Vc = &VT[cur][0];
        __builtin_amdgcn_s_setprio(1);
        #pragma unroll
        for (int kc = 0; kc < 2; kc++) {
            const int pchunk = ((kc*4 + quad) ^ (ml & 7)) * 8;
            const bf16x8 pf0 = *(const bf16x8*)&Pb[(wv*32 + ml) * 64 + pchunk];
            const bf16x8 pf1 = *(const bf16x8*)&Pb[(wv*32 + 16 + ml) * 64 + pchunk];
            #pragma unroll
            for (int nt = 0; nt < 8; nt++) {
                const bf16x8 vf = *(const bf16x8*)
                    &Vc[(nt*16 + ml) * 64 + (((kc*4 + quad) ^ (ml & 7)) * 8)];
                oacc[0][nt] = MFMA16(pf0, vf, oacc[0][nt], 0, 0, 0);
                oacc[1][nt] = MFMA16(pf1, vf, oacc[1][nt], 0, 0, 0);
            }
        }
        __builtin_amdgcn_s_setprio(0);

        __syncthreads();   // drain prefetch + WAR for next tile
    }
    #undef STAGE

    // ---- epilogue: divide by l, store A bf16 [s][1024] ----
    const float linv0 = 1.0f / l_run[0];
    const float linv1 = 1.0f / l_run[1];
    f32x4 li[2];
    #pragma unroll
    for (int r = 0; r < 4; r++) {
        li[0][r] = __shfl(linv0, quad*20 + r);
        li[1][r] = __shfl(linv1, quad*20 + r);
    }
    const long abase = (long)b * SEQ * FDIM;
    #pragma unroll
    for (int mt = 0; mt < 2; mt++)
        #pragma unroll
        for (int nt = 0; nt < 8; nt++) {
            const int dim = nt*16 + ml;
            u16* dst = ((dim < 64) ? Ar_g : Ai_g) + abase
                     + (long)(q0 + wv*32 + mt*16 + quad*4) * FDIM + h * HD + (dim & 63);
            #pragma unroll
            for (int r = 0; r < 4; r++)
                dst[(long)r * FDIM] = f2bf(oacc[mt][nt][r] * li[mt][r]);
        }
}

// =====================================================================
// O-projection GEMM v3 (verified round 3).
// =====================================================================
__global__ __launch_bounds__(256)
void oproj_bf16(const u16* __restrict__ Ar_all, const u16* __restrict__ Ai_all,
                const u16* __restrict__ Wtor,
                const float* __restrict__ bor, const float* __restrict__ boi,
                float* __restrict__ out)
{
    __shared__ u16 XsR[2][128 * 32], XsI[2][128 * 32];
    __shared__ u16 WsR[2][128 * 32], WsI[2][128 * 32];

    const int b = blockIdx.z;
    const u16* ar = Ar_all + (long)b * SEQ * FDIM;
    const u16* ai = Ai_all + (long)b * SEQ * FDIM;
    const u16* wr = Wtor;
    const u16* wi = Wtor + (long)FDIM * FDIM;
    float* outR = out + (long)b * SEQ * FDIM;
    float* outI = out + (long)2 * SEQ * FDIM + (long)b * SEQ * FDIM;

    const int tid = threadIdx.x;
    const int n0  = blockIdx.x * 128;
    const int m0  = blockIdx.y * 128;

    const int lane = tid & 63;
    const int wv   = tid >> 6;
    const int mwo  = (wv >> 1) * 64;
    const int nwo  = (wv & 1) * 64;
    const int ml   = lane & 15;
    const int kg   = lane >> 4;

    const int lr = lane >> 2;
    const int xc = (((lane & 3) ^ (lr & 3)) * 8);
    const int rc = ((kg ^ (ml & 3)) * 8);

    f32x4 accr[4][4], acci[4][4];
    #pragma unroll
    for (int i = 0; i < 4; i++)
        #pragma unroll
        for (int j = 0; j < 4; j++) { accr[i][j] = (f32x4)(0.0f); acci[i][j] = (f32x4)(0.0f); }

    #define OSTAGE(bufi, kk)                                                     \
        do {                                                                     \
            _Pragma("unroll")                                                    \
            for (int sub = 0; sub < 2; sub++) {                                  \
                const int rs  = wv * 32 + sub * 16;                              \
                const int row = rs + lr;                                         \
                g2l16(ar + (long)(m0 + row) * FDIM + (kk) + xc, &XsR[bufi][rs * 32]); \
                g2l16(ai + (long)(m0 + row) * FDIM + (kk) + xc, &XsI[bufi][rs * 32]); \
                g2l16(wr + (long)(n0 + row) * FDIM + (kk) + xc, &WsR[bufi][rs * 32]); \
                g2l16(wi + (long)(n0 + row) * FDIM + (kk) + xc, &WsI[bufi][rs * 32]); \
            }                                                                    \
        } while (0)

    int buf = 0;
    OSTAGE(0, 0);
    __syncthreads();

    for (int k0 = 0; k0 < FDIM; k0 += 32) {
        if (k0 + 32 < FDIM) OSTAGE(buf ^ 1, k0 + 32);

        bf16x8 arf[4], aif[4], naif[4], brf[4], bif[4];
        #pragma unroll
        for (int i = 0; i < 4; i++) {
            arf[i] = *(const bf16x8*)&XsR[buf][(mwo + 16*i + ml) * 32 + rc];
            union { bf16x8 v; u32 w[4]; } u;
            u.v = *(const bf16x8*)&XsI[buf][(mwo + 16*i + ml) * 32 + rc];
            aif[i] = u.v;
            u.w[0] ^= 0x80008000u; u.w[1] ^= 0x80008000u;
            u.w[2] ^= 0x80008000u; u.w[3] ^= 0x80008000u;
            naif[i] = u.v;
        }
        #pragma unroll
        for (int j = 0; j < 4; j++) {
            brf[j] = *(const bf16x8*)&WsR[buf][(nwo + 16*j + ml) * 32 + rc];
            bif[j] = *(const bf16x8*)&WsI[buf][(nwo + 16*j + ml) * 32 + rc];
        }
        #pragma unroll
        for (int i = 0; i < 4; i++)
            #pragma unroll
            for (int j = 0; j < 4; j++) {
                accr[i][j] = MFMA16(arf[i],  brf[j], accr[i][j], 0, 0, 0);
                accr[i][j] = MFMA16(naif[i], bif[j], accr[i][j], 0, 0, 0);
                acci[i][j] = MFMA16(arf[i],  bif[j], acci[i][j], 0, 0, 0);
                acci[i][j] = MFMA16(aif[i],  brf[j], acci[i][j], 0, 0, 0);
            }

        __syncthreads();
        buf ^= 1;
    }
    #undef OSTAGE

    #pragma unroll
    for (int j = 0; j < 4; j++) {
        const int n = n0 + nwo + 16*j + ml;
        const float bre = bor[n];
        const float bim = boi[n];
        #pragma unroll
        for (int i = 0; i < 4; i++) {
            #pragma unroll
            for (int r = 0; r < 4; r++) {
                const int m = m0 + mwo + 16*i + kg*4 + r;
                const long addr = (long)m * FDIM + n;
                outR[addr] = accr[i][j][r] + bre;
                outI[addr] = acci[i][j][r] + bim;
            }
        }
    }
}

extern "C" void kernel_launch(void* const* d_in, const int* in_sizes, int n_in,
                              void* d_out, int out_size, void* d_ws, size_t ws_size,
                              hipStream_t stream)
{
    const float* x_r  = (const float*)d_in[0];
    const float* x_i  = (const float*)d_in[1];
    const float* mask = (const float*)d_in[2];
    const float *Wq_r = (const float*)d_in[3],  *Wq_i = (const float*)d_in[4];
    const float *bq_r = (const float*)d_in[5],  *bq_i = (const float*)d_in[6];
    const float *Wk_r = (const float*)d_in[7],  *Wk_i = (const float*)d_in[8];
    const float *bk_r = (const float*)d_in[9],  *bk_i = (const float*)d_in[10];
    const float *Wv_r = (const float*)d_in[11], *Wv_i = (const float*)d_in[12];
    const float *bv_r = (const float*)d_in[13], *bv_i = (const float*)d_in[14];
    const float *Wo_r = (const float*)d_in[15], *Wo_i = (const float*)d_in[16];
    const float *bo_r = (const float*)d_in[17], *bo_i = (const float*)d_in[18];

    u16* ws = (u16*)d_ws;
    const long TS = (long)2 * SEQ * FDIM;
    const long WT = (long)FDIM * FDIM;
    u16 *Qr = ws,          *Qi = ws + TS;
    u16 *Kr = ws + 2*TS,   *Ki = ws + 3*TS;
    u16 *Vtr = ws + 4*TS,  *Vti = ws + 5*TS;
    u16 *Ar = ws + 6*TS,   *Ai = ws + 7*TS;
    u16 *Xbr = Ar,         *Xbi = Ai;          // aliased (proj-phase only)
    u16 *Wt  = ws + 8*TS;

    convert_x<<<dim3(2048), 256, 0, stream>>>(x_r, x_i, Xbr, Xbi);
    convert_w<<<dim3(16, 16, 8), 256, 0, stream>>>(Wq_r, Wq_i, Wk_r, Wk_i,
                                                   Wv_r, Wv_i, Wo_r, Wo_i, Wt);

    proj_bf16<<<dim3(8, 16, 6), 256, 0, stream>>>(Xbr, Xbi, Wt,
        bq_r, bq_i, bk_r, bk_i, bv_r, bv_i, ws);

    attn_mfma<<<dim3(SEQ / 128, NH, 2), 256, 0, stream>>>(Qr, Qi, Kr, Ki, Vtr, Vti,
                                                          mask, Ar, Ai);

    oproj_bf16<<<dim3(8, 16, 2), 256, 0, stream>>>(Ar, Ai, Wt + 6*WT,
                                                   bo_r, bo_i, (float*)d_out);
}

// Round 10
// 450.229 us; speedup vs baseline: 1.1178x; 1.1178x over previous
//
#include <hip/hip_runtime.h>
#include <hip/hip_bf16.h>

typedef unsigned short u16;
typedef unsigned int   u32;
typedef __attribute__((ext_vector_type(8))) short bf16x8;
typedef __attribute__((ext_vector_type(4))) float f32x4;

#define FDIM 1024
#define NH   16
#define HD   64
#define SEQ  2048

#define MFMA16 __builtin_amdgcn_mfma_f32_16x16x32_bf16

__device__ __forceinline__ u16 f2bf(float f) {
    __hip_bfloat16 h = __float2bfloat16(f);
    return *reinterpret_cast<u16*>(&h);
}

// async global->LDS, 16B per lane. LDS dest is wave-uniform base + lane*16.
__device__ __forceinline__ void g2l16(const u16* g, u16* l) {
    __builtin_amdgcn_global_load_lds(
        (const __attribute__((address_space(1))) unsigned int*)g,
        (__attribute__((address_space(3))) unsigned int*)l,
        16, 0, 0);
}

// =====================================================================
// One-shot fp32 -> bf16 conversion of X (both batches, re+im).
// =====================================================================
__global__ __launch_bounds__(256)
void convert_x(const float* __restrict__ xr, const float* __restrict__ xi,
               u16* __restrict__ dr, u16* __restrict__ di)
{
    const long n4 = (long)2 * SEQ * FDIM / 4;
    for (long i = (long)blockIdx.x * blockDim.x + threadIdx.x; i < n4;
         i += (long)gridDim.x * blockDim.x) {
        float4 v = ((const float4*)xr)[i];
        ushort4 o;
        o.x = f2bf(v.x); o.y = f2bf(v.y); o.z = f2bf(v.z); o.w = f2bf(v.w);
        ((ushort4*)dr)[i] = o;
        v = ((const float4*)xi)[i];
        o.x = f2bf(v.x); o.y = f2bf(v.y); o.z = f2bf(v.z); o.w = f2bf(v.w);
        ((ushort4*)di)[i] = o;
    }
}

// =====================================================================
// One-shot fp32 W [k][n] -> bf16 W^T [n][k] for all 8 weight matrices.
// =====================================================================
__global__ __launch_bounds__(256)
void convert_w(const float* __restrict__ W0, const float* __restrict__ W1,
               const float* __restrict__ W2, const float* __restrict__ W3,
               const float* __restrict__ W4, const float* __restrict__ W5,
               const float* __restrict__ W6, const float* __restrict__ W7,
               u16* __restrict__ wt_base)
{
    __shared__ u16 T[64][68];
    const int z = blockIdx.z;
    const float* W = (z == 0) ? W0 : (z == 1) ? W1 : (z == 2) ? W2 : (z == 3) ? W3
                   : (z == 4) ? W4 : (z == 5) ? W5 : (z == 6) ? W6 : W7;
    u16* Wt = wt_base + (long)z * FDIM * FDIM;
    const int n0 = blockIdx.x * 64, k0 = blockIdx.y * 64;
    const int tid = threadIdx.x;
    const int cr = tid & 15, rr = tid >> 4;
    #pragma unroll
    for (int p = 0; p < 4; p++) {
        const int k = p * 16 + rr;
        float4 v = *(const float4*)&W[(long)(k0 + k) * FDIM + n0 + cr * 4];
        T[k][cr*4 + 0] = f2bf(v.x); T[k][cr*4 + 1] = f2bf(v.y);
        T[k][cr*4 + 2] = f2bf(v.z); T[k][cr*4 + 3] = f2bf(v.w);
    }
    __syncthreads();
    #pragma unroll
    for (int p = 0; p < 4; p++) {
        const int n = p * 16 + rr;
        ushort4 o;
        o.x = T[cr*4 + 0][n]; o.y = T[cr*4 + 1][n];
        o.z = T[cr*4 + 2][n]; o.w = T[cr*4 + 3][n];
        *(ushort4*)&Wt[(long)(n0 + n) * FDIM + k0 + cr*4] = o;
    }
}

// =====================================================================
// Projection GEMM v3 (verified round 3): pure bf16, double-buffered
// one-tile-ahead prefetch, chunk-swizzled LDS.
// =====================================================================
__global__ __launch_bounds__(256)
void proj_bf16(const u16* __restrict__ Xr_g, const u16* __restrict__ Xi_g,
               const u16* __restrict__ Wt_base,
               const float* __restrict__ bqr, const float* __restrict__ bqi,
               const float* __restrict__ bkr, const float* __restrict__ bki,
               const float* __restrict__ bvr, const float* __restrict__ bvi,
               u16* __restrict__ ws)
{
    __shared__ u16 XsR[2][128 * 32], XsI[2][128 * 32];
    __shared__ u16 WsR[2][128 * 32], WsI[2][128 * 32];

    const int z = blockIdx.z, t = z % 3, b = z / 3;
    const u16* xr = Xr_g + (long)b * SEQ * FDIM;
    const u16* xi = Xi_g + (long)b * SEQ * FDIM;
    const long WT = (long)FDIM * FDIM;
    const u16* wr = Wt_base + (long)(2 * t) * WT;
    const u16* wi = wr + WT;
    const float* br = (t == 0) ? bqr : (t == 1) ? bkr : bvr;
    const float* bi = (t == 0) ? bqi : (t == 1) ? bki : bvi;
    const long TS = (long)2 * SEQ * FDIM;
    u16* outR = ws + (long)(t * 2) * TS + (long)b * SEQ * FDIM;
    u16* outI = outR + TS;

    const int tid = threadIdx.x;
    const int n0  = blockIdx.x * 128;
    const int m0  = blockIdx.y * 128;

    const int lane = tid & 63;
    const int wv   = tid >> 6;
    const int mwo  = (wv >> 1) * 64;
    const int nwo  = (wv & 1) * 64;
    const int ml   = lane & 15;
    const int kg   = lane >> 4;

    const int lr = lane >> 2;
    const int xc = (((lane & 3) ^ (lr & 3)) * 8);
    const int rc = ((kg ^ (ml & 3)) * 8);

    f32x4 accr[4][4], acci[4][4];
    #pragma unroll
    for (int i = 0; i < 4; i++)
        #pragma unroll
        for (int j = 0; j < 4; j++) { accr[i][j] = (f32x4)(0.0f); acci[i][j] = (f32x4)(0.0f); }

    #define PSTAGE(bufi, kk)                                                     \
        do {                                                                     \
            _Pragma("unroll")                                                    \
            for (int sub = 0; sub < 2; sub++) {                                  \
                const int rs  = wv * 32 + sub * 16;                              \
                const int row = rs + lr;                                         \
                g2l16(xr + (long)(m0 + row) * FDIM + (kk) + xc, &XsR[bufi][rs * 32]); \
                g2l16(xi + (long)(m0 + row) * FDIM + (kk) + xc, &XsI[bufi][rs * 32]); \
                g2l16(wr + (long)(n0 + row) * FDIM + (kk) + xc, &WsR[bufi][rs * 32]); \
                g2l16(wi + (long)(n0 + row) * FDIM + (kk) + xc, &WsI[bufi][rs * 32]); \
            }                                                                    \
        } while (0)

    int buf = 0;
    PSTAGE(0, 0);
    __syncthreads();

    for (int k0 = 0; k0 < FDIM; k0 += 32) {
        if (k0 + 32 < FDIM) PSTAGE(buf ^ 1, k0 + 32);

        bf16x8 ar[4], ai[4], nai[4], brf[4], bif[4];
        #pragma unroll
        for (int i = 0; i < 4; i++) {
            ar[i] = *(const bf16x8*)&XsR[buf][(mwo + 16*i + ml) * 32 + rc];
            union { bf16x8 v; u32 w[4]; } u;
            u.v = *(const bf16x8*)&XsI[buf][(mwo + 16*i + ml) * 32 + rc];
            ai[i] = u.v;
            u.w[0] ^= 0x80008000u; u.w[1] ^= 0x80008000u;
            u.w[2] ^= 0x80008000u; u.w[3] ^= 0x80008000u;
            nai[i] = u.v;
        }
        #pragma unroll
        for (int j = 0; j < 4; j++) {
            brf[j] = *(const bf16x8*)&WsR[buf][(nwo + 16*j + ml) * 32 + rc];
            bif[j] = *(const bf16x8*)&WsI[buf][(nwo + 16*j + ml) * 32 + rc];
        }
        #pragma unroll
        for (int i = 0; i < 4; i++)
            #pragma unroll
            for (int j = 0; j < 4; j++) {
                accr[i][j] = MFMA16(ar[i],  brf[j], accr[i][j], 0, 0, 0);
                accr[i][j] = MFMA16(nai[i], bif[j], accr[i][j], 0, 0, 0);
                acci[i][j] = MFMA16(ar[i],  bif[j], acci[i][j], 0, 0, 0);
                acci[i][j] = MFMA16(ai[i],  brf[j], acci[i][j], 0, 0, 0);
            }

        __syncthreads();
        buf ^= 1;
    }
    #undef PSTAGE

    #pragma unroll
    for (int j = 0; j < 4; j++) {
        const int n = n0 + nwo + 16*j + ml;
        const int hh = n >> 6, d = n & 63;
        const float bre = br[n];
        const float bim = bi[n];
        #pragma unroll
        for (int i = 0; i < 4; i++) {
            const int mb = m0 + mwo + 16*i + kg*4;
            if (t < 2) {
                #pragma unroll
                for (int r = 0; r < 4; r++) {
                    const long addr = ((long)hh * SEQ + (mb + r)) * HD + d;
                    outR[addr] = f2bf(accr[i][j][r] + bre);
                    outI[addr] = f2bf(acci[i][j][r] + bim);
                }
            } else {
                const long addr = ((long)hh * HD + d) * SEQ + mb;
                ushort4 vr, vi;
                vr.x = f2bf(accr[i][j][0] + bre); vr.y = f2bf(accr[i][j][1] + bre);
                vr.z = f2bf(accr[i][j][2] + bre); vr.w = f2bf(accr[i][j][3] + bre);
                vi.x = f2bf(acci[i][j][0] + bim); vi.y = f2bf(acci[i][j][1] + bim);
                vi.z = f2bf(acci[i][j][2] + bim); vi.w = f2bf(acci[i][j][3] + bim);
                *(ushort4*)&outR[addr] = vr;
                *(ushort4*)&outI[addr] = vi;
            }
        }
    }
}

// =====================================================================
// MFMA flash attention v6: occupancy-first. QBLK=64 (each wave owns 16
// q-rows, mechanical restriction of verified round-7 code), SINGLE-
// buffered K/V LDS (32 KiB) -> 4 blocks/CU (grid 1024 = 4/CU), vs the
// old 2/CU grid cap. Per tile: sync / STAGE+mask / sync / QK / barrier /
// softmax+P(alias K) / PV. Cross-block TLP hides drain+softmax latency.
// Round-7 softmax internals kept verbatim (v5 deltas reverted).
// =====================================================================
__global__ __launch_bounds__(256, 4)
void attn_mfma(const u16* __restrict__ Qr_g, const u16* __restrict__ Qi_g,
               const u16* __restrict__ Kr_g, const u16* __restrict__ Ki_g,
               const u16* __restrict__ Vtr_g, const u16* __restrict__ Vti_g,
               const float* __restrict__ mask_g,
               u16* __restrict__ Ar_g, u16* __restrict__ Ai_g)
{
    __shared__ u16 KT[64 * 128];   // [key][dim 0..127 = re||im], chunk-swizzled
    __shared__ u16 VT[128 * 64];   // [dim re||im][key], chunk-swizzled

    const int tid  = threadIdx.x;
    const int lane = tid & 63;
    const int wv   = tid >> 6;
    const int ml   = lane & 15;
    const int quad = lane >> 4;

    // ---- XCD swizzle: 32 q-blocks of one (h,b) share an XCD. Bijective:
    //      1024 blocks -> 8 residues x 4 (h,b)-groups x 32 q-blocks.
    const int L   = blockIdx.x + (blockIdx.y << 5) + (blockIdx.z << 9);
    const int xcd = L & 7, qq = L >> 3;
    const int q0  = (qq & 31) * 64;
    const int g   = ((qq >> 5) << 3) | xcd;
    const int h   = g & 15;
    const int b   = g >> 4;
    const long hb  = ((long)b * NH + h) * SEQ * HD;
    const float* mask = mask_g + (long)b * SEQ;

    // ---- Q fragments: 16 q-rows per wave, in registers all kernel ----
    bf16x8 qf[4];
    {
        const long row = hb + (long)(q0 + wv*16 + ml) * HD;
        qf[0] = *(const bf16x8*)(Qr_g + row + quad*8);
        qf[1] = *(const bf16x8*)(Qr_g + row + 32 + quad*8);
        qf[2] = *(const bf16x8*)(Qi_g + row + quad*8);
        qf[3] = *(const bf16x8*)(Qi_g + row + 32 + quad*8);
    }

    // ---- staging source pointers (pre-swizzled, lane-constant) ----
    const u16* srcK[4];
    #pragma unroll
    for (int ii = 0; ii < 4; ii++) {
        const int rk = wv*16 + ii*4 + (lane >> 4);
        const int c  = (lane & 15) ^ (rk & 7);
        srcK[ii] = ((c < 8) ? Kr_g : Ki_g) + hb + (long)rk * HD + (c & 7) * 8;
    }
    const u16* srcV[4];
    #pragma unroll
    for (int jj = 0; jj < 4; jj++) {
        const int dv = wv*32 + jj*8 + (lane >> 3);
        const int c  = (lane & 7) ^ (dv & 7);
        srcV[jj] = ((dv < 64) ? Vtr_g : Vti_g) + hb + (long)(dv & 63) * SEQ + c * 8;
    }

    #define STAGE()                                                             \
        do {                                                                    \
            _Pragma("unroll")                                                   \
            for (int ii = 0; ii < 4; ii++)                                      \
                g2l16(srcK[ii], &KT[(wv*16 + ii*4) * 128]);                     \
            _Pragma("unroll")                                                   \
            for (int jj = 0; jj < 4; jj++)                                      \
                g2l16(srcV[jj], &VT[(wv*32 + jj*8) * 64]);                      \
            _Pragma("unroll")                                                   \
            for (int ii = 0; ii < 4; ii++) srcK[ii] += 64 * HD;                 \
            _Pragma("unroll")                                                   \
            for (int jj = 0; jj < 4; jj++) srcV[jj] += 64;                      \
        } while (0)

    f32x4 oacc[8];
    #pragma unroll
    for (int nt = 0; nt < 8; nt++) oacc[nt] = (f32x4)(0.0f);
    float m_run = -3.0e38f;
    float l_run = 0.0f;
    const float scale = 0.125f;

    const int NT = SEQ / 64;
    for (int t = 0; t < NT; ++t) {
        if (t) __syncthreads();     // prev tile fully consumed before restage
        STAGE();

        f32x4 mrow[4];
        #pragma unroll
        for (int mt = 0; mt < 4; mt++)
            mrow[mt] = *(const f32x4*)(mask + t*64 + mt*16 + quad*4);

        __syncthreads();            // staged K/V + mask landed (full drain)

        // ---- scores: S^T[key][q] ----
        f32x4 sacc[4];
        #pragma unroll
        for (int mt = 0; mt < 4; mt++) sacc[mt] = (f32x4)(0.0f);
        __builtin_amdgcn_s_setprio(1);
        #pragma unroll
        for (int mt = 0; mt < 4; mt++)
            #pragma unroll
            for (int kc = 0; kc < 4; kc++) {
                const bf16x8 kf = *(const bf16x8*)
                    &KT[(mt*16 + ml) * 128 + (((kc*4 + quad) ^ (ml & 7)) * 8)];
                sacc[mt] = MFMA16(kf, qf[kc], sacc[mt], 0, 0, 0);
            }
        __builtin_amdgcn_s_setprio(0);

        // all waves done reading K; P may overwrite it
        asm volatile("s_barrier" ::: "memory");

        u16* Pb = (u16*)&KT[0];     // alias: P as [64][64], same swizzle key (ml)
        float sv[4][4];
        #pragma unroll
        for (int mt = 0; mt < 4; mt++)
            #pragma unroll
            for (int r = 0; r < 4; r++)
                sv[mt][r] = sacc[mt][r] * scale + (1.0f - mrow[mt][r]) * -1.0e9f;

        // tree max (depth 4)
        float mA = fmaxf(fmaxf(sv[0][0], sv[0][1]), fmaxf(sv[0][2], sv[0][3]));
        float mB = fmaxf(fmaxf(sv[1][0], sv[1][1]), fmaxf(sv[1][2], sv[1][3]));
        float mC = fmaxf(fmaxf(sv[2][0], sv[2][1]), fmaxf(sv[2][2], sv[2][3]));
        float mD = fmaxf(fmaxf(sv[3][0], sv[3][1]), fmaxf(sv[3][2], sv[3][3]));
        float mx = fmaxf(fmaxf(mA, mB), fmaxf(mC, mD));
        mx = fmaxf(mx, __shfl_xor(mx, 16));
        mx = fmaxf(mx, __shfl_xor(mx, 32));
        const float mn = fmaxf(m_run, mx);
        const float al = __expf(m_run - mn);

        float p[4][4];
        #pragma unroll
        for (int mt = 0; mt < 4; mt++) {
            p[mt][0] = __expf(sv[mt][0] - mn);
            p[mt][1] = __expf(sv[mt][1] - mn);
            p[mt][2] = __expf(sv[mt][2] - mn);
            p[mt][3] = __expf(sv[mt][3] - mn);
        }
        const int qrow = wv*16 + ml;
        #pragma unroll
        for (int mt = 0; mt < 4; mt++) {
            ushort4 pb;
            pb.x = f2bf(p[mt][0]); pb.y = f2bf(p[mt][1]);
            pb.z = f2bf(p[mt][2]); pb.w = f2bf(p[mt][3]);
            *(ushort4*)&Pb[(long)qrow * 64
                           + (((mt*2 + (quad >> 1)) ^ (ml & 7)) * 8)
                           + (quad & 1) * 4] = pb;
        }
        // tree sum
        float s0 = (p[0][0] + p[0][1]) + (p[0][2] + p[0][3]);
        float s1 = (p[1][0] + p[1][1]) + (p[1][2] + p[1][3]);
        float s2 = (p[2][0] + p[2][1]) + (p[2][2] + p[2][3]);
        float s3 = (p[3][0] + p[3][1]) + (p[3][2] + p[3][3]);
        float ps = (s0 + s1) + (s2 + s3);
        ps += __shfl_xor(ps, 16);
        ps += __shfl_xor(ps, 32);
        l_run = l_run * al + ps;
        m_run = mn;

        // rescale O (bank-spread shfl, value-identical sources)
        f32x4 al4;
        #pragma unroll
        for (int r = 0; r < 4; r++)
            al4[r] = __shfl(al, quad*20 + r);
        #pragma unroll
        for (int nt = 0; nt < 8; nt++) oacc[nt] *= al4;

        // ---- PV (P rows are intra-wave; no extra barrier needed) ----
        __builtin_amdgcn_s_setprio(1);
        #pragma unroll
        for (int kc = 0; kc < 2; kc++) {
            const int pchunk = ((kc*4 + quad) ^ (ml & 7)) * 8;
            const bf16x8 pf = *(const bf16x8*)&Pb[(long)qrow * 64 + pchunk];
            #pragma unroll
            for (int nt = 0; nt < 8; nt++) {
                const bf16x8 vf = *(const bf16x8*)
                    &VT[(nt*16 + ml) * 64 + (((kc*4 + quad) ^ (ml & 7)) * 8)];
                oacc[nt] = MFMA16(pf, vf, oacc[nt], 0, 0, 0);
            }
        }
        __builtin_amdgcn_s_setprio(0);
    }
    #undef STAGE

    // ---- epilogue: divide by l, store A bf16 [s][1024] ----
    const float linv = 1.0f / l_run;
    f32x4 li;
    #pragma unroll
    for (int r = 0; r < 4; r++)
        li[r] = __shfl(linv, quad*20 + r);
    const long abase = (long)b * SEQ * FDIM;
    #pragma unroll
    for (int nt = 0; nt < 8; nt++) {
        const int dim = nt*16 + ml;
        u16* dst = ((dim < 64) ? Ar_g : Ai_g) + abase
                 + (long)(q0 + wv*16 + quad*4) * FDIM + h * HD + (dim & 63);
        #pragma unroll
        for (int r = 0; r < 4; r++)
            dst[(long)r * FDIM] = f2bf(oacc[nt][r] * li[r]);
    }
}

// =====================================================================
// O-projection GEMM v3 (verified round 3).
// =====================================================================
__global__ __launch_bounds__(256)
void oproj_bf16(const u16* __restrict__ Ar_all, const u16* __restrict__ Ai_all,
                const u16* __restrict__ Wtor,
                const float* __restrict__ bor, const float* __restrict__ boi,
                float* __restrict__ out)
{
    __shared__ u16 XsR[2][128 * 32], XsI[2][128 * 32];
    __shared__ u16 WsR[2][128 * 32], WsI[2][128 * 32];

    const int b = blockIdx.z;
    const u16* ar = Ar_all + (long)b * SEQ * FDIM;
    const u16* ai = Ai_all + (long)b * SEQ * FDIM;
    const u16* wr = Wtor;
    const u16* wi = Wtor + (long)FDIM * FDIM;
    float* outR = out + (long)b * SEQ * FDIM;
    float* outI = out + (long)2 * SEQ * FDIM + (long)b * SEQ * FDIM;

    const int tid = threadIdx.x;
    const int n0  = blockIdx.x * 128;
    const int m0  = blockIdx.y * 128;

    const int lane = tid & 63;
    const int wv   = tid >> 6;
    const int mwo  = (wv >> 1) * 64;
    const int nwo  = (wv & 1) * 64;
    const int ml   = lane & 15;
    const int kg   = lane >> 4;

    const int lr = lane >> 2;
    const int xc = (((lane & 3) ^ (lr & 3)) * 8);
    const int rc = ((kg ^ (ml & 3)) * 8);

    f32x4 accr[4][4], acci[4][4];
    #pragma unroll
    for (int i = 0; i < 4; i++)
        #pragma unroll
        for (int j = 0; j < 4; j++) { accr[i][j] = (f32x4)(0.0f); acci[i][j] = (f32x4)(0.0f); }

    #define OSTAGE(bufi, kk)                                                     \
        do {                                                                     \
            _Pragma("unroll")                                                    \
            for (int sub = 0; sub < 2; sub++) {                                  \
                const int rs  = wv * 32 + sub * 16;                              \
                const int row = rs + lr;                                         \
                g2l16(ar + (long)(m0 + row) * FDIM + (kk) + xc, &XsR[bufi][rs * 32]); \
                g2l16(ai + (long)(m0 + row) * FDIM + (kk) + xc, &XsI[bufi][rs * 32]); \
                g2l16(wr + (long)(n0 + row) * FDIM + (kk) + xc, &WsR[bufi][rs * 32]); \
                g2l16(wi + (long)(n0 + row) * FDIM + (kk) + xc, &WsI[bufi][rs * 32]); \
            }                                                                    \
        } while (0)

    int buf = 0;
    OSTAGE(0, 0);
    __syncthreads();

    for (int k0 = 0; k0 < FDIM; k0 += 32) {
        if (k0 + 32 < FDIM) OSTAGE(buf ^ 1, k0 + 32);

        bf16x8 arf[4], aif[4], naif[4], brf[4], bif[4];
        #pragma unroll
        for (int i = 0; i < 4; i++) {
            arf[i] = *(const bf16x8*)&XsR[buf][(mwo + 16*i + ml) * 32 + rc];
            union { bf16x8 v; u32 w[4]; } u;
            u.v = *(const bf16x8*)&XsI[buf][(mwo + 16*i + ml) * 32 + rc];
            aif[i] = u.v;
            u.w[0] ^= 0x80008000u; u.w[1] ^= 0x80008000u;
            u.w[2] ^= 0x80008000u; u.w[3] ^= 0x80008000u;
            naif[i] = u.v;
        }
        #pragma unroll
        for (int j = 0; j < 4; j++) {
            brf[j] = *(const bf16x8*)&WsR[buf][(nwo + 16*j + ml) * 32 + rc];
            bif[j] = *(const bf16x8*)&WsI[buf][(nwo + 16*j + ml) * 32 + rc];
        }
        #pragma unroll
        for (int i = 0; i < 4; i++)
            #pragma unroll
            for (int j = 0; j < 4; j++) {
                accr[i][j] = MFMA16(arf[i],  brf[j], accr[i][j], 0, 0, 0);
                accr[i][j] = MFMA16(naif[i], bif[j], accr[i][j], 0, 0, 0);
                acci[i][j] = MFMA16(arf[i],  bif[j], acci[i][j], 0, 0, 0);
                acci[i][j] = MFMA16(aif[i],  brf[j], acci[i][j], 0, 0, 0);
            }

        __syncthreads();
        buf ^= 1;
    }
    #undef OSTAGE

    #pragma unroll
    for (int j = 0; j < 4; j++) {
        const int n = n0 + nwo + 16*j + ml;
        const float bre = bor[n];
        const float bim = boi[n];
        #pragma unroll
        for (int i = 0; i < 4; i++) {
            #pragma unroll
            for (int r = 0; r < 4; r++) {
                const int m = m0 + mwo + 16*i + kg*4 + r;
                const long addr = (long)m * FDIM + n;
                outR[addr] = accr[i][j][r] + bre;
                outI[addr] = acci[i][j][r] + bim;
            }
        }
    }
}

extern "C" void kernel_launch(void* const* d_in, const int* in_sizes, int n_in,
                              void* d_out, int out_size, void* d_ws, size_t ws_size,
                              hipStream_t stream)
{
    const float* x_r  = (const float*)d_in[0];
    const float* x_i  = (const float*)d_in[1];
    const float* mask = (const float*)d_in[2];
    const float *Wq_r = (const float*)d_in[3],  *Wq_i = (const float*)d_in[4];
    const float *bq_r = (const float*)d_in[5],  *bq_i = (const float*)d_in[6];
    const float *Wk_r = (const float*)d_in[7],  *Wk_i = (const float*)d_in[8];
    const float *bk_r = (const float*)d_in[9],  *bk_i = (const float*)d_in[10];
    const float *Wv_r = (const float*)d_in[11], *Wv_i = (const float*)d_in[12];
    const float *bv_r = (const float*)d_in[13], *bv_i = (const float*)d_in[14];
    const float *Wo_r = (const float*)d_in[15], *Wo_i = (const float*)d_in[16];
    const float *bo_r = (const float*)d_in[17], *bo_i = (const float*)d_in[18];

    u16* ws = (u16*)d_ws;
    const long TS = (long)2 * SEQ * FDIM;
    const long WT = (long)FDIM * FDIM;
    u16 *Qr = ws,          *Qi = ws + TS;
    u16 *Kr = ws + 2*TS,   *Ki = ws + 3*TS;
    u16 *Vtr = ws + 4*TS,  *Vti = ws + 5*TS;
    u16 *Ar = ws + 6*TS,   *Ai = ws + 7*TS;
    u16 *Xbr = Ar,         *Xbi = Ai;          // aliased (proj-phase only)
    u16 *Wt  = ws + 8*TS;

    convert_x<<<dim3(2048), 256, 0, stream>>>(x_r, x_i, Xbr, Xbi);
    convert_w<<<dim3(16, 16, 8), 256, 0, stream>>>(Wq_r, Wq_i, Wk_r, Wk_i,
                                                   Wv_r, Wv_i, Wo_r, Wo_i, Wt);

    proj_bf16<<<dim3(8, 16, 6), 256, 0, stream>>>(Xbr, Xbi, Wt,
        bq_r, bq_i, bk_r, bk_i, bv_r, bv_i, ws);

    attn_mfma<<<dim3(SEQ / 64, NH, 2), 256, 0, stream>>>(Qr, Qi, Kr, Ki, Vtr, Vti,
                                                         mask, Ar, Ai);

    oproj_bf16<<<dim3(8, 16, 2), 256, 0, stream>>>(Ar, Ai, Wt + 6*WT,
                                                   bo_r, bo_i, (float*)d_out);
}

// Round 11
// 392.811 us; speedup vs baseline: 1.2812x; 1.1462x over previous
//
#include <hip/hip_runtime.h>
#include <hip/hip_bf16.h>

typedef unsigned short u16;
typedef unsigned int   u32;
typedef __attribute__((ext_vector_type(8))) short bf16x8;
typedef __attribute__((ext_vector_type(4))) float f32x4;

#define FDIM 1024
#define NH   16
#define HD   64
#define SEQ  2048

#define MFMA16 __builtin_amdgcn_mfma_f32_16x16x32_bf16

__device__ __forceinline__ u16 f2bf(float f) {
    __hip_bfloat16 h = __float2bfloat16(f);
    return *reinterpret_cast<u16*>(&h);
}

// async global->LDS, 16B per lane. LDS dest is wave-uniform base + lane*16.
__device__ __forceinline__ void g2l16(const u16* g, u16* l) {
    __builtin_amdgcn_global_load_lds(
        (const __attribute__((address_space(1))) unsigned int*)g,
        (__attribute__((address_space(3))) unsigned int*)l,
        16, 0, 0);
}

// =====================================================================
// One-shot fp32 -> bf16 conversion of X (both batches, re+im).
// =====================================================================
__global__ __launch_bounds__(256)
void convert_x(const float* __restrict__ xr, const float* __restrict__ xi,
               u16* __restrict__ dr, u16* __restrict__ di)
{
    const long n4 = (long)2 * SEQ * FDIM / 4;
    for (long i = (long)blockIdx.x * blockDim.x + threadIdx.x; i < n4;
         i += (long)gridDim.x * blockDim.x) {
        float4 v = ((const float4*)xr)[i];
        ushort4 o;
        o.x = f2bf(v.x); o.y = f2bf(v.y); o.z = f2bf(v.z); o.w = f2bf(v.w);
        ((ushort4*)dr)[i] = o;
        v = ((const float4*)xi)[i];
        o.x = f2bf(v.x); o.y = f2bf(v.y); o.z = f2bf(v.z); o.w = f2bf(v.w);
        ((ushort4*)di)[i] = o;
    }
}

// =====================================================================
// One-shot fp32 W [k][n] -> bf16 W^T [n][k] for all 8 weight matrices.
// =====================================================================
__global__ __launch_bounds__(256)
void convert_w(const float* __restrict__ W0, const float* __restrict__ W1,
               const float* __restrict__ W2, const float* __restrict__ W3,
               const float* __restrict__ W4, const float* __restrict__ W5,
               const float* __restrict__ W6, const float* __restrict__ W7,
               u16* __restrict__ wt_base)
{
    __shared__ u16 T[64][68];
    const int z = blockIdx.z;
    const float* W = (z == 0) ? W0 : (z == 1) ? W1 : (z == 2) ? W2 : (z == 3) ? W3
                   : (z == 4) ? W4 : (z == 5) ? W5 : (z == 6) ? W6 : W7;
    u16* Wt = wt_base + (long)z * FDIM * FDIM;
    const int n0 = blockIdx.x * 64, k0 = blockIdx.y * 64;
    const int tid = threadIdx.x;
    const int cr = tid & 15, rr = tid >> 4;
    #pragma unroll
    for (int p = 0; p < 4; p++) {
        const int k = p * 16 + rr;
        float4 v = *(const float4*)&W[(long)(k0 + k) * FDIM + n0 + cr * 4];
        T[k][cr*4 + 0] = f2bf(v.x); T[k][cr*4 + 1] = f2bf(v.y);
        T[k][cr*4 + 2] = f2bf(v.z); T[k][cr*4 + 3] = f2bf(v.w);
    }
    __syncthreads();
    #pragma unroll
    for (int p = 0; p < 4; p++) {
        const int n = p * 16 + rr;
        ushort4 o;
        o.x = T[cr*4 + 0][n]; o.y = T[cr*4 + 1][n];
        o.z = T[cr*4 + 2][n]; o.w = T[cr*4 + 3][n];
        *(ushort4*)&Wt[(long)(n0 + n) * FDIM + k0 + cr*4] = o;
    }
}

// =====================================================================
// Projection GEMM v4: 64x128 tile (M-split of verified v3) for 3
// blocks/CU (LDS 48KB dbuf). Same dbuf prefetch, chunk swizzle, inner
// loop, epilogue algebra; acc [2][4]; 2 M-waves x 2 N-waves.
// =====================================================================
__global__ __launch_bounds__(256, 3)
void proj_bf16(const u16* __restrict__ Xr_g, const u16* __restrict__ Xi_g,
               const u16* __restrict__ Wt_base,
               const float* __restrict__ bqr, const float* __restrict__ bqi,
               const float* __restrict__ bkr, const float* __restrict__ bki,
               const float* __restrict__ bvr, const float* __restrict__ bvi,
               u16* __restrict__ ws)
{
    __shared__ u16 XsR[2][64 * 32],  XsI[2][64 * 32];    // 16 KiB
    __shared__ u16 WsR[2][128 * 32], WsI[2][128 * 32];   // 32 KiB

    const int z = blockIdx.z, t = z % 3, b = z / 3;
    const u16* xr = Xr_g + (long)b * SEQ * FDIM;
    const u16* xi = Xi_g + (long)b * SEQ * FDIM;
    const long WT = (long)FDIM * FDIM;
    const u16* wr = Wt_base + (long)(2 * t) * WT;
    const u16* wi = wr + WT;
    const float* br = (t == 0) ? bqr : (t == 1) ? bkr : bvr;
    const float* bi = (t == 0) ? bqi : (t == 1) ? bki : bvi;
    const long TS = (long)2 * SEQ * FDIM;
    u16* outR = ws + (long)(t * 2) * TS + (long)b * SEQ * FDIM;
    u16* outI = outR + TS;

    const int tid = threadIdx.x;
    const int n0  = blockIdx.x * 128;
    const int m0  = blockIdx.y * 64;

    const int lane = tid & 63;
    const int wv   = tid >> 6;
    const int mwo  = (wv >> 1) * 32;     // 2 M-waves x 32 rows
    const int nwo  = (wv & 1) * 64;      // 2 N-waves x 64 cols
    const int ml   = lane & 15;
    const int kg   = lane >> 4;

    const int lr = lane >> 2;
    const int xc = (((lane & 3) ^ (lr & 3)) * 8);
    const int rc = ((kg ^ (ml & 3)) * 8);

    f32x4 accr[2][4], acci[2][4];
    #pragma unroll
    for (int i = 0; i < 2; i++)
        #pragma unroll
        for (int j = 0; j < 4; j++) { accr[i][j] = (f32x4)(0.0f); acci[i][j] = (f32x4)(0.0f); }

    #define PSTAGE(bufi, kk)                                                     \
        do {                                                                     \
            const int rsx  = wv * 16;                                            \
            const int rowx = rsx + lr;                                           \
            g2l16(xr + (long)(m0 + rowx) * FDIM + (kk) + xc, &XsR[bufi][rsx * 32]); \
            g2l16(xi + (long)(m0 + rowx) * FDIM + (kk) + xc, &XsI[bufi][rsx * 32]); \
            _Pragma("unroll")                                                    \
            for (int sub = 0; sub < 2; sub++) {                                  \
                const int rs  = wv * 32 + sub * 16;                              \
                const int row = rs + lr;                                         \
                g2l16(wr + (long)(n0 + row) * FDIM + (kk) + xc, &WsR[bufi][rs * 32]); \
                g2l16(wi + (long)(n0 + row) * FDIM + (kk) + xc, &WsI[bufi][rs * 32]); \
            }                                                                    \
        } while (0)

    int buf = 0;
    PSTAGE(0, 0);
    __syncthreads();

    for (int k0 = 0; k0 < FDIM; k0 += 32) {
        if (k0 + 32 < FDIM) PSTAGE(buf ^ 1, k0 + 32);

        bf16x8 ar[2], ai[2], nai[2], brf[4], bif[4];
        #pragma unroll
        for (int i = 0; i < 2; i++) {
            ar[i] = *(const bf16x8*)&XsR[buf][(mwo + 16*i + ml) * 32 + rc];
            union { bf16x8 v; u32 w[4]; } u;
            u.v = *(const bf16x8*)&XsI[buf][(mwo + 16*i + ml) * 32 + rc];
            ai[i] = u.v;
            u.w[0] ^= 0x80008000u; u.w[1] ^= 0x80008000u;
            u.w[2] ^= 0x80008000u; u.w[3] ^= 0x80008000u;
            nai[i] = u.v;
        }
        #pragma unroll
        for (int j = 0; j < 4; j++) {
            brf[j] = *(const bf16x8*)&WsR[buf][(nwo + 16*j + ml) * 32 + rc];
            bif[j] = *(const bf16x8*)&WsI[buf][(nwo + 16*j + ml) * 32 + rc];
        }
        #pragma unroll
        for (int i = 0; i < 2; i++)
            #pragma unroll
            for (int j = 0; j < 4; j++) {
                accr[i][j] = MFMA16(ar[i],  brf[j], accr[i][j], 0, 0, 0);
                accr[i][j] = MFMA16(nai[i], bif[j], accr[i][j], 0, 0, 0);
                acci[i][j] = MFMA16(ar[i],  bif[j], acci[i][j], 0, 0, 0);
                acci[i][j] = MFMA16(ai[i],  brf[j], acci[i][j], 0, 0, 0);
            }

        __syncthreads();
        buf ^= 1;
    }
    #undef PSTAGE

    #pragma unroll
    for (int j = 0; j < 4; j++) {
        const int n = n0 + nwo + 16*j + ml;
        const int hh = n >> 6, d = n & 63;
        const float bre = br[n];
        const float bim = bi[n];
        #pragma unroll
        for (int i = 0; i < 2; i++) {
            const int mb = m0 + mwo + 16*i + kg*4;
            if (t < 2) {
                #pragma unroll
                for (int r = 0; r < 4; r++) {
                    const long addr = ((long)hh * SEQ + (mb + r)) * HD + d;
                    outR[addr] = f2bf(accr[i][j][r] + bre);
                    outI[addr] = f2bf(acci[i][j][r] + bim);
                }
            } else {
                const long addr = ((long)hh * HD + d) * SEQ + mb;
                ushort4 vr, vi;
                vr.x = f2bf(accr[i][j][0] + bre); vr.y = f2bf(accr[i][j][1] + bre);
                vr.z = f2bf(accr[i][j][2] + bre); vr.w = f2bf(accr[i][j][3] + bre);
                vi.x = f2bf(acci[i][j][0] + bim); vi.y = f2bf(acci[i][j][1] + bim);
                vi.z = f2bf(acci[i][j][2] + bim); vi.w = f2bf(acci[i][j][3] + bim);
                *(ushort4*)&outR[addr] = vr;
                *(ushort4*)&outI[addr] = vi;
            }
        }
    }
}

// =====================================================================
// MFMA flash attention v6 (verified round 10): QBLK=64, single-buffer,
// 4 blocks/CU, XCD swizzle.
// =====================================================================
__global__ __launch_bounds__(256, 4)
void attn_mfma(const u16* __restrict__ Qr_g, const u16* __restrict__ Qi_g,
               const u16* __restrict__ Kr_g, const u16* __restrict__ Ki_g,
               const u16* __restrict__ Vtr_g, const u16* __restrict__ Vti_g,
               const float* __restrict__ mask_g,
               u16* __restrict__ Ar_g, u16* __restrict__ Ai_g)
{
    __shared__ u16 KT[64 * 128];
    __shared__ u16 VT[128 * 64];

    const int tid  = threadIdx.x;
    const int lane = tid & 63;
    const int wv   = tid >> 6;
    const int ml   = lane & 15;
    const int quad = lane >> 4;

    const int L   = blockIdx.x + (blockIdx.y << 5) + (blockIdx.z << 9);
    const int xcd = L & 7, qq = L >> 3;
    const int q0  = (qq & 31) * 64;
    const int g   = ((qq >> 5) << 3) | xcd;
    const int h   = g & 15;
    const int b   = g >> 4;
    const long hb  = ((long)b * NH + h) * SEQ * HD;
    const float* mask = mask_g + (long)b * SEQ;

    bf16x8 qf[4];
    {
        const long row = hb + (long)(q0 + wv*16 + ml) * HD;
        qf[0] = *(const bf16x8*)(Qr_g + row + quad*8);
        qf[1] = *(const bf16x8*)(Qr_g + row + 32 + quad*8);
        qf[2] = *(const bf16x8*)(Qi_g + row + quad*8);
        qf[3] = *(const bf16x8*)(Qi_g + row + 32 + quad*8);
    }

    const u16* srcK[4];
    #pragma unroll
    for (int ii = 0; ii < 4; ii++) {
        const int rk = wv*16 + ii*4 + (lane >> 4);
        const int c  = (lane & 15) ^ (rk & 7);
        srcK[ii] = ((c < 8) ? Kr_g : Ki_g) + hb + (long)rk * HD + (c & 7) * 8;
    }
    const u16* srcV[4];
    #pragma unroll
    for (int jj = 0; jj < 4; jj++) {
        const int dv = wv*32 + jj*8 + (lane >> 3);
        const int c  = (lane & 7) ^ (dv & 7);
        srcV[jj] = ((dv < 64) ? Vtr_g : Vti_g) + hb + (long)(dv & 63) * SEQ + c * 8;
    }

    #define STAGE()                                                             \
        do {                                                                    \
            _Pragma("unroll")                                                   \
            for (int ii = 0; ii < 4; ii++)                                      \
                g2l16(srcK[ii], &KT[(wv*16 + ii*4) * 128]);                     \
            _Pragma("unroll")                                                   \
            for (int jj = 0; jj < 4; jj++)                                      \
                g2l16(srcV[jj], &VT[(wv*32 + jj*8) * 64]);                      \
            _Pragma("unroll")                                                   \
            for (int ii = 0; ii < 4; ii++) srcK[ii] += 64 * HD;                 \
            _Pragma("unroll")                                                   \
            for (int jj = 0; jj < 4; jj++) srcV[jj] += 64;                      \
        } while (0)

    f32x4 oacc[8];
    #pragma unroll
    for (int nt = 0; nt < 8; nt++) oacc[nt] = (f32x4)(0.0f);
    float m_run = -3.0e38f;
    float l_run = 0.0f;
    const float scale = 0.125f;

    const int NT = SEQ / 64;
    for (int t = 0; t < NT; ++t) {
        if (t) __syncthreads();
        STAGE();

        f32x4 mrow[4];
        #pragma unroll
        for (int mt = 0; mt < 4; mt++)
            mrow[mt] = *(const f32x4*)(mask + t*64 + mt*16 + quad*4);

        __syncthreads();

        f32x4 sacc[4];
        #pragma unroll
        for (int mt = 0; mt < 4; mt++) sacc[mt] = (f32x4)(0.0f);
        __builtin_amdgcn_s_setprio(1);
        #pragma unroll
        for (int mt = 0; mt < 4; mt++)
            #pragma unroll
            for (int kc = 0; kc < 4; kc++) {
                const bf16x8 kf = *(const bf16x8*)
                    &KT[(mt*16 + ml) * 128 + (((kc*4 + quad) ^ (ml & 7)) * 8)];
                sacc[mt] = MFMA16(kf, qf[kc], sacc[mt], 0, 0, 0);
            }
        __builtin_amdgcn_s_setprio(0);

        asm volatile("s_barrier" ::: "memory");

        u16* Pb = (u16*)&KT[0];
        float sv[4][4];
        #pragma unroll
        for (int mt = 0; mt < 4; mt++)
            #pragma unroll
            for (int r = 0; r < 4; r++)
                sv[mt][r] = sacc[mt][r] * scale + (1.0f - mrow[mt][r]) * -1.0e9f;

        float mA = fmaxf(fmaxf(sv[0][0], sv[0][1]), fmaxf(sv[0][2], sv[0][3]));
        float mB = fmaxf(fmaxf(sv[1][0], sv[1][1]), fmaxf(sv[1][2], sv[1][3]));
        float mC = fmaxf(fmaxf(sv[2][0], sv[2][1]), fmaxf(sv[2][2], sv[2][3]));
        float mD = fmaxf(fmaxf(sv[3][0], sv[3][1]), fmaxf(sv[3][2], sv[3][3]));
        float mx = fmaxf(fmaxf(mA, mB), fmaxf(mC, mD));
        mx = fmaxf(mx, __shfl_xor(mx, 16));
        mx = fmaxf(mx, __shfl_xor(mx, 32));
        const float mn = fmaxf(m_run, mx);
        const float al = __expf(m_run - mn);

        float p[4][4];
        #pragma unroll
        for (int mt = 0; mt < 4; mt++) {
            p[mt][0] = __expf(sv[mt][0] - mn);
            p[mt][1] = __expf(sv[mt][1] - mn);
            p[mt][2] = __expf(sv[mt][2] - mn);
            p[mt][3] = __expf(sv[mt][3] - mn);
        }
        const int qrow = wv*16 + ml;
        #pragma unroll
        for (int mt = 0; mt < 4; mt++) {
            ushort4 pb;
            pb.x = f2bf(p[mt][0]); pb.y = f2bf(p[mt][1]);
            pb.z = f2bf(p[mt][2]); pb.w = f2bf(p[mt][3]);
            *(ushort4*)&Pb[(long)qrow * 64
                           + (((mt*2 + (quad >> 1)) ^ (ml & 7)) * 8)
                           + (quad & 1) * 4] = pb;
        }
        float s0 = (p[0][0] + p[0][1]) + (p[0][2] + p[0][3]);
        float s1 = (p[1][0] + p[1][1]) + (p[1][2] + p[1][3]);
        float s2 = (p[2][0] + p[2][1]) + (p[2][2] + p[2][3]);
        float s3 = (p[3][0] + p[3][1]) + (p[3][2] + p[3][3]);
        float ps = (s0 + s1) + (s2 + s3);
        ps += __shfl_xor(ps, 16);
        ps += __shfl_xor(ps, 32);
        l_run = l_run * al + ps;
        m_run = mn;

        f32x4 al4;
        #pragma unroll
        for (int r = 0; r < 4; r++)
            al4[r] = __shfl(al, quad*20 + r);
        #pragma unroll
        for (int nt = 0; nt < 8; nt++) oacc[nt] *= al4;

        __builtin_amdgcn_s_setprio(1);
        #pragma unroll
        for (int kc = 0; kc < 2; kc++) {
            const int pchunk = ((kc*4 + quad) ^ (ml & 7)) * 8;
            const bf16x8 pf = *(const bf16x8*)&Pb[(long)qrow * 64 + pchunk];
            #pragma unroll
            for (int nt = 0; nt < 8; nt++) {
                const bf16x8 vf = *(const bf16x8*)
                    &VT[(nt*16 + ml) * 64 + (((kc*4 + quad) ^ (ml & 7)) * 8)];
                oacc[nt] = MFMA16(pf, vf, oacc[nt], 0, 0, 0);
            }
        }
        __builtin_amdgcn_s_setprio(0);
    }
    #undef STAGE

    const float linv = 1.0f / l_run;
    f32x4 li;
    #pragma unroll
    for (int r = 0; r < 4; r++)
        li[r] = __shfl(linv, quad*20 + r);
    const long abase = (long)b * SEQ * FDIM;
    #pragma unroll
    for (int nt = 0; nt < 8; nt++) {
        const int dim = nt*16 + ml;
        u16* dst = ((dim < 64) ? Ar_g : Ai_g) + abase
                 + (long)(q0 + wv*16 + quad*4) * FDIM + h * HD + (dim & 63);
        #pragma unroll
        for (int r = 0; r < 4; r++)
            dst[(long)r * FDIM] = f2bf(oacc[nt][r] * li[r]);
    }
}

// =====================================================================
// O-projection GEMM v4: 64x128 tile (M-split of verified v3), grid 512
// blocks -> 2 blocks/CU (was 256 = 1/CU). LDS 48KB dbuf.
// =====================================================================
__global__ __launch_bounds__(256, 3)
void oproj_bf16(const u16* __restrict__ Ar_all, const u16* __restrict__ Ai_all,
                const u16* __restrict__ Wtor,
                const float* __restrict__ bor, const float* __restrict__ boi,
                float* __restrict__ out)
{
    __shared__ u16 XsR[2][64 * 32],  XsI[2][64 * 32];
    __shared__ u16 WsR[2][128 * 32], WsI[2][128 * 32];

    const int b = blockIdx.z;
    const u16* ar = Ar_all + (long)b * SEQ * FDIM;
    const u16* ai = Ai_all + (long)b * SEQ * FDIM;
    const u16* wr = Wtor;
    const u16* wi = Wtor + (long)FDIM * FDIM;
    float* outR = out + (long)b * SEQ * FDIM;
    float* outI = out + (long)2 * SEQ * FDIM + (long)b * SEQ * FDIM;

    const int tid = threadIdx.x;
    const int n0  = blockIdx.x * 128;
    const int m0  = blockIdx.y * 64;

    const int lane = tid & 63;
    const int wv   = tid >> 6;
    const int mwo  = (wv >> 1) * 32;
    const int nwo  = (wv & 1) * 64;
    const int ml   = lane & 15;
    const int kg   = lane >> 4;

    const int lr = lane >> 2;
    const int xc = (((lane & 3) ^ (lr & 3)) * 8);
    const int rc = ((kg ^ (ml & 3)) * 8);

    f32x4 accr[2][4], acci[2][4];
    #pragma unroll
    for (int i = 0; i < 2; i++)
        #pragma unroll
        for (int j = 0; j < 4; j++) { accr[i][j] = (f32x4)(0.0f); acci[i][j] = (f32x4)(0.0f); }

    #define OSTAGE(bufi, kk)                                                     \
        do {                                                                     \
            const int rsx  = wv * 16;                                            \
            const int rowx = rsx + lr;                                           \
            g2l16(ar + (long)(m0 + rowx) * FDIM + (kk) + xc, &XsR[bufi][rsx * 32]); \
            g2l16(ai + (long)(m0 + rowx) * FDIM + (kk) + xc, &XsI[bufi][rsx * 32]); \
            _Pragma("unroll")                                                    \
            for (int sub = 0; sub < 2; sub++) {                                  \
                const int rs  = wv * 32 + sub * 16;                              \
                const int row = rs + lr;                                         \
                g2l16(wr + (long)(n0 + row) * FDIM + (kk) + xc, &WsR[bufi][rs * 32]); \
                g2l16(wi + (long)(n0 + row) * FDIM + (kk) + xc, &WsI[bufi][rs * 32]); \
            }                                                                    \
        } while (0)

    int buf = 0;
    OSTAGE(0, 0);
    __syncthreads();

    for (int k0 = 0; k0 < FDIM; k0 += 32) {
        if (k0 + 32 < FDIM) OSTAGE(buf ^ 1, k0 + 32);

        bf16x8 arf[2], aif[2], naif[2], brf[4], bif[4];
        #pragma unroll
        for (int i = 0; i < 2; i++) {
            arf[i] = *(const bf16x8*)&XsR[buf][(mwo + 16*i + ml) * 32 + rc];
            union { bf16x8 v; u32 w[4]; } u;
            u.v = *(const bf16x8*)&XsI[buf][(mwo + 16*i + ml) * 32 + rc];
            aif[i] = u.v;
            u.w[0] ^= 0x80008000u; u.w[1] ^= 0x80008000u;
            u.w[2] ^= 0x80008000u; u.w[3] ^= 0x80008000u;
            naif[i] = u.v;
        }
        #pragma unroll
        for (int j = 0; j < 4; j++) {
            brf[j] = *(const bf16x8*)&WsR[buf][(nwo + 16*j + ml) * 32 + rc];
            bif[j] = *(const bf16x8*)&WsI[buf][(nwo + 16*j + ml) * 32 + rc];
        }
        #pragma unroll
        for (int i = 0; i < 2; i++)
            #pragma unroll
            for (int j = 0; j < 4; j++) {
                accr[i][j] = MFMA16(arf[i],  brf[j], accr[i][j], 0, 0, 0);
                accr[i][j] = MFMA16(naif[i], bif[j], accr[i][j], 0, 0, 0);
                acci[i][j] = MFMA16(arf[i],  bif[j], acci[i][j], 0, 0, 0);
                acci[i][j] = MFMA16(aif[i],  brf[j], acci[i][j], 0, 0, 0);
            }

        __syncthreads();
        buf ^= 1;
    }
    #undef OSTAGE

    #pragma unroll
    for (int j = 0; j < 4; j++) {
        const int n = n0 + nwo + 16*j + ml;
        const float bre = bor[n];
        const float bim = boi[n];
        #pragma unroll
        for (int i = 0; i < 2; i++) {
            #pragma unroll
            for (int r = 0; r < 4; r++) {
                const int m = m0 + mwo + 16*i + kg*4 + r;
                const long addr = (long)m * FDIM + n;
                outR[addr] = accr[i][j][r] + bre;
                outI[addr] = acci[i][j][r] + bim;
            }
        }
    }
}

extern "C" void kernel_launch(void* const* d_in, const int* in_sizes, int n_in,
                              void* d_out, int out_size, void* d_ws, size_t ws_size,
                              hipStream_t stream)
{
    const float* x_r  = (const float*)d_in[0];
    const float* x_i  = (const float*)d_in[1];
    const float* mask = (const float*)d_in[2];
    const float *Wq_r = (const float*)d_in[3],  *Wq_i = (const float*)d_in[4];
    const float *bq_r = (const float*)d_in[5],  *bq_i = (const float*)d_in[6];
    const float *Wk_r = (const float*)d_in[7],  *Wk_i = (const float*)d_in[8];
    const float *bk_r = (const float*)d_in[9],  *bk_i = (const float*)d_in[10];
    const float *Wv_r = (const float*)d_in[11], *Wv_i = (const float*)d_in[12];
    const float *bv_r = (const float*)d_in[13], *bv_i = (const float*)d_in[14];
    const float *Wo_r = (const float*)d_in[15], *Wo_i = (const float*)d_in[16];
    const float *bo_r = (const float*)d_in[17], *bo_i = (const float*)d_in[18];

    u16* ws = (u16*)d_ws;
    const long TS = (long)2 * SEQ * FDIM;
    const long WT = (long)FDIM * FDIM;
    u16 *Qr = ws,          *Qi = ws + TS;
    u16 *Kr = ws + 2*TS,   *Ki = ws + 3*TS;
    u16 *Vtr = ws + 4*TS,  *Vti = ws + 5*TS;
    u16 *Ar = ws + 6*TS,   *Ai = ws + 7*TS;
    u16 *Xbr = Ar,         *Xbi = Ai;          // aliased (proj-phase only)
    u16 *Wt  = ws + 8*TS;

    convert_x<<<dim3(2048), 256, 0, stream>>>(x_r, x_i, Xbr, Xbi);
    convert_w<<<dim3(16, 16, 8), 256, 0, stream>>>(Wq_r, Wq_i, Wk_r, Wk_i,
                                                   Wv_r, Wv_i, Wo_r, Wo_i, Wt);

    proj_bf16<<<dim3(8, 32, 6), 256, 0, stream>>>(Xbr, Xbi, Wt,
        bq_r, bq_i, bk_r, bk_i, bv_r, bv_i, ws);

    attn_mfma<<<dim3(SEQ / 64, NH, 2), 256, 0, stream>>>(Qr, Qi, Kr, Ki, Vtr, Vti,
                                                         mask, Ar, Ai);

    oproj_bf16<<<dim3(8, 32, 2), 256, 0, stream>>>(Ar, Ai, Wt + 6*WT,
                                                   bo_r, bo_i, (float*)d_out);
}